// Round 6
// baseline (562.143 us; speedup 1.0000x reference)
//
#include <hip/hip_runtime.h>
#include <hip/hip_cooperative_groups.h>
#include <hip/hip_bf16.h>
#include <math.h>

namespace cg = cooperative_groups;

#define TDIM 1024
#define FDIM 1024
#define DDIM 512

typedef __attribute__((ext_vector_type(8))) short bf16x8;
typedef __attribute__((ext_vector_type(4))) float f32x4;

__device__ __forceinline__ float posenc_val(int t, int c) {
    int j = c >> 1;
    float dv = expf(-9.210340371976184f * (float)(2 * j) * (1.0f / 512.0f));
    float arg = (float)t * dv;
    return (c & 1) ? cosf(arg) : sinf(arg);
}

__device__ __forceinline__ ushort f2bf(float f) {
    __hip_bfloat16 h = __float2bfloat16(f);
    return *reinterpret_cast<ushort*>(&h);
}

// ================= small-M (32-row) split-K GEMM body =================
template<int BK>
__device__ __forceinline__ void g32_body(
    const float* X, long lda,
    const float* Pin, int KCx, const float* xbias, int xrelu,
    const float* W, long ldb,
    float* Pout, int N, int K,
    int bx, int by, float* lds)
{
    float (*Xs)[BK + 4] = (float (*)[BK + 4])lds;
    float (*Ws)[64]     = (float (*)[64])(lds + 32 * (BK + 4));
    const int tid = threadIdx.x;
    const int n0 = bx * 64, k0 = by * BK;

    {
        const int m  = tid >> 3;
        const int ks = (tid & 7) * (BK / 8);
        if (Pin) {
            #pragma unroll
            for (int j = 0; j < BK / 32; ++j) {
                float4 a = make_float4(0.f, 0.f, 0.f, 0.f);
                for (int c = 0; c < KCx; ++c) {
                    float4 v = *(const float4*)(Pin + (size_t)(c * 32 + m) * K + k0 + ks + j * 4);
                    a.x += v.x; a.y += v.y; a.z += v.z; a.w += v.w;
                }
                if (xbias) {
                    float4 bv = *(const float4*)(xbias + k0 + ks + j * 4);
                    a.x += bv.x; a.y += bv.y; a.z += bv.z; a.w += bv.w;
                }
                if (xrelu) {
                    a.x = fmaxf(a.x, 0.f); a.y = fmaxf(a.y, 0.f);
                    a.z = fmaxf(a.z, 0.f); a.w = fmaxf(a.w, 0.f);
                }
                *(float4*)&Xs[m][ks + j * 4] = a;
            }
        } else {
            const float* src = X + (size_t)m * lda + k0 + ks;
            #pragma unroll
            for (int j = 0; j < BK / 32; ++j)
                *(float4*)&Xs[m][ks + j * 4] = *(const float4*)(src + j * 4);
        }
    }
    #pragma unroll
    for (int it = 0; it < BK / 16; ++it) {
        int e4  = it * 256 + tid;
        int row = e4 >> 4;
        int c4  = e4 & 15;
        *(float4*)&Ws[row][c4 * 4] = *(const float4*)(W + (size_t)(k0 + row) * ldb + n0 + c4 * 4);
    }
    __syncthreads();

    const int tx = tid & 31;
    const int ty = tid >> 5;
    float acc[4][2] = {};
    #pragma unroll 8
    for (int k = 0; k < BK; k += 4) {
        float4 xv[4];
        #pragma unroll
        for (int i = 0; i < 4; ++i) xv[i] = *(const float4*)&Xs[ty * 4 + i][k];
        #pragma unroll
        for (int j = 0; j < 4; ++j) {
            float2 w = *(const float2*)&Ws[k + j][tx * 2];
            #pragma unroll
            for (int i = 0; i < 4; ++i) {
                float x = ((const float*)&xv[i])[j];
                acc[i][0] = fmaf(x, w.x, acc[i][0]);
                acc[i][1] = fmaf(x, w.y, acc[i][1]);
            }
        }
    }
    float* dst = Pout + (size_t)by * 32 * N;
    #pragma unroll
    for (int i = 0; i < 4; ++i)
        *(float2*)(dst + (size_t)(ty * 4 + i) * N + n0 + tx * 2) = make_float2(acc[i][0], acc[i][1]);
}

// ================= convert+transpose body: W[K][ldw] -> Wt[N][K] bf16 =================
__device__ __forceinline__ void convT_body(const float* W, int ldw, int col0,
                                           ushort* Wt, int K, int bx, int by, float* lds)
{
    float (*t)[33] = (float (*)[33])lds;
    const int k0 = by * 32, n0 = bx * 32;
    const int x = threadIdx.x & 31, y = threadIdx.x >> 5;
    #pragma unroll
    for (int yy = y; yy < 32; yy += 8)
        t[yy][x] = W[(size_t)(k0 + yy) * ldw + col0 + n0 + x];
    __syncthreads();
    #pragma unroll
    for (int yy = y; yy < 32; yy += 8)
        Wt[(size_t)(n0 + yy) * K + k0 + x] = f2bf(t[x][yy]);
}

// ================= MFMA bf16 GEMM body (64x64 tile, 4 waves 2x2) =================
__device__ __forceinline__ void mfma_body(
    const ushort* A, long lda,
    const ushort* Bt, const float* bias,
    float* C, int ldc, ushort* Cbf, int ldcb,
    int K, int relu, int addpe,
    int bx, int by, char* smem)
{
    ushort* Al = (ushort*)smem;
    ushort* Bl = Al + 64 * 64;
    const int tid = threadIdx.x;
    const int m0 = by * 64;
    const int n0 = bx * 64;
    const int lane = tid & 63;
    const int wv = tid >> 6;
    const int wr = wv >> 1, wc = wv & 1;
    const int fr = lane & 15, g = lane >> 4;

    f32x4 acc[2][2] = {};

    const int r0 = tid >> 3;
    const int c0 = tid & 7;

    for (int k0 = 0; k0 < K; k0 += 64) {
        #pragma unroll
        for (int it = 0; it < 2; ++it) {
            int r = r0 + it * 32;
            uint4 va = *(const uint4*)(A + (size_t)(m0 + r) * lda + k0 + c0 * 8);
            *(uint4*)((char*)Al + r * 128 + ((c0 ^ (r & 7)) << 4)) = va;
            uint4 vb = *(const uint4*)(Bt + (size_t)(n0 + r) * K + k0 + c0 * 8);
            *(uint4*)((char*)Bl + r * 128 + ((c0 ^ (r & 7)) << 4)) = vb;
        }
        __syncthreads();
        #pragma unroll
        for (int h = 0; h < 2; ++h) {
            bf16x8 af[2], bff[2];
            #pragma unroll
            for (int i = 0; i < 2; ++i) {
                int row = wr * 32 + i * 16 + fr;
                af[i] = *(const bf16x8*)((const char*)Al + row * 128 + (((h * 4 + g) ^ (row & 7)) << 4));
                int col = wc * 32 + i * 16 + fr;
                bff[i] = *(const bf16x8*)((const char*)Bl + col * 128 + (((h * 4 + g) ^ (col & 7)) << 4));
            }
            #pragma unroll
            for (int i = 0; i < 2; ++i)
                #pragma unroll
                for (int j = 0; j < 2; ++j)
                    acc[i][j] = __builtin_amdgcn_mfma_f32_16x16x32_bf16(af[i], bff[j], acc[i][j], 0, 0, 0);
        }
        __syncthreads();
    }

    #pragma unroll
    for (int j = 0; j < 2; ++j) {
        int n = n0 + wc * 32 + j * 16 + fr;
        float bv = bias ? bias[n] : 0.f;
        #pragma unroll
        for (int i = 0; i < 2; ++i) {
            #pragma unroll
            for (int q = 0; q < 4; ++q) {
                int m = m0 + wr * 32 + i * 16 + g * 4 + q;
                float v = acc[i][j][q] + bv;
                if (relu) v = fmaxf(v, 0.f);
                if (addpe) v += posenc_val(m, n);
                if (C)   C[(size_t)m * ldc + n] = v;
                if (Cbf) Cbf[(size_t)m * ldcb + n] = f2bf(v);
            }
        }
    }
}

// ================= scores body =================
__device__ __forceinline__ void scores_body(const float* QKV, float* Psc, int bxs, int byc, char* smem)
{
    float (*Kt)[132] = (float (*)[132])smem;
    float (*Qt)[133] = (float (*)[133])(smem + 64 * 132 * 4);
    const int tid = threadIdx.x;
    const int s0 = bxs * 64;
    const int k0 = byc * 128;

    #pragma unroll
    for (int it = 0; it < 8; ++it) {
        int e4 = it * 256 + tid;
        int r  = e4 >> 5;
        int c4 = e4 & 31;
        float4 v = *(const float4*)(QKV + (size_t)(s0 + r) * 1536 + 512 + k0 + c4 * 4);
        *(float4*)&Kt[r][c4 * 4] = v;
    }
    #pragma unroll
    for (int it = 0; it < 4; ++it) {
        int e4 = it * 256 + tid;
        int r  = e4 >> 5;
        int c4 = e4 & 31;
        float4 v = *(const float4*)(QKV + (size_t)(32 * r + 31) * 1536 + k0 + c4 * 4);
        Qt[r][c4 * 4 + 0] = v.x;
        Qt[r][c4 * 4 + 1] = v.y;
        Qt[r][c4 * 4 + 2] = v.z;
        Qt[r][c4 * 4 + 3] = v.w;
    }
    __syncthreads();

    const int i  = tid & 31;
    const int sg = tid >> 5;
    float acc[8] = {};
    for (int k = 0; k < 128; ++k) {
        float q = Qt[i][k];
        #pragma unroll
        for (int j = 0; j < 8; ++j)
            acc[j] = fmaf(Kt[sg * 8 + j][k], q, acc[j]);
    }
    float* dst = Psc + (size_t)byc * 1024 * 32;
    #pragma unroll
    for (int j = 0; j < 8; ++j)
        dst[(size_t)(s0 + sg * 8 + j) * 32 + i] = acc[j];
}

// ================= softmax body (row i) =================
__device__ __forceinline__ void softmax_body(const float* Psc, const float* lam_p,
                                             float* D, int i, float* lds)
{
    float* sc1 = lds;
    float* sc2 = lds + 1024;
    float* red = lds + 2048;
    const int tid = threadIdx.x;
    const float scale = 0.08838834764831845f; // 1/sqrt(128)
    for (int s = tid; s < 1024; s += 256) {
        float a = Psc[(size_t)s * 32 + i] + Psc[(size_t)(1024 + s) * 32 + i];
        float b = Psc[(size_t)(2048 + s) * 32 + i] + Psc[(size_t)(3072 + s) * 32 + i];
        sc1[s] = a * scale;
        sc2[s] = b * scale;
    }
    __syncthreads();
    float m1 = -INFINITY, m2 = -INFINITY;
    for (int s = tid; s < 1024; s += 256) { m1 = fmaxf(m1, sc1[s]); m2 = fmaxf(m2, sc2[s]); }
    red[tid] = m1; __syncthreads();
    for (int o = 128; o > 0; o >>= 1) { if (tid < o) red[tid] = fmaxf(red[tid], red[tid + o]); __syncthreads(); }
    m1 = red[0]; __syncthreads();
    red[tid] = m2; __syncthreads();
    for (int o = 128; o > 0; o >>= 1) { if (tid < o) red[tid] = fmaxf(red[tid], red[tid + o]); __syncthreads(); }
    m2 = red[0]; __syncthreads();
    float t1 = 0.f, t2 = 0.f;
    for (int s = tid; s < 1024; s += 256) { t1 += expf(sc1[s] - m1); t2 += expf(sc2[s] - m2); }
    red[tid] = t1; __syncthreads();
    for (int o = 128; o > 0; o >>= 1) { if (tid < o) red[tid] += red[tid + o]; __syncthreads(); }
    t1 = red[0]; __syncthreads();
    red[tid] = t2; __syncthreads();
    for (int o = 128; o > 0; o >>= 1) { if (tid < o) red[tid] += red[tid + o]; __syncthreads(); }
    t2 = red[0]; __syncthreads();
    const float inv1 = 1.f / t1, inv2 = 1.f / t2;
    const float lam = *lam_p;
    for (int s = tid; s < 1024; s += 256)
        D[(size_t)i * 1024 + s] = expf(sc1[s] - m1) * inv1 - lam * expf(sc2[s] - m2) * inv2;
}

// ================= LN body (row m): Y = LN(R + sum(P)+bias)*g + b =================
__device__ __forceinline__ void ln_body(const float* Pin, int KC, const float* bias,
                                        const float* R, const float* g, const float* b,
                                        float* Y, int m, float* red)
{
    const int tid = threadIdx.x;
    float v0 = bias ? bias[tid] : 0.f;
    float v1 = bias ? bias[tid + 256] : 0.f;
    for (int c = 0; c < KC; ++c) {
        v0 += Pin[(size_t)(c * 32 + m) * 512 + tid];
        v1 += Pin[(size_t)(c * 32 + m) * 512 + tid + 256];
    }
    v0 += R[m * 512 + tid];
    v1 += R[m * 512 + tid + 256];
    red[tid] = v0 + v1; __syncthreads();
    for (int o = 128; o > 0; o >>= 1) { if (tid < o) red[tid] += red[tid + o]; __syncthreads(); }
    const float mu = red[0] * (1.0f / 512.0f);
    __syncthreads();
    float d0 = v0 - mu, d1 = v1 - mu;
    red[tid] = d0 * d0 + d1 * d1; __syncthreads();
    for (int o = 128; o > 0; o >>= 1) { if (tid < o) red[tid] += red[tid + o]; __syncthreads(); }
    const float var = red[0] * (1.0f / 512.0f);
    const float inv = 1.0f / sqrtf(var + 1e-5f);
    Y[m * 512 + tid]       = d0 * inv * g[tid]       + b[tid];
    Y[m * 512 + 256 + tid] = d1 * inv * g[256 + tid] + b[256 + tid];
}

// ================= mega kernel params =================
struct KP {
    const float *features, *enc_w1, *enc_b1, *enc_w2, *enc_b2, *qkv_w, *qkv_b, *lam;
    const float *out_w, *out_b, *ln1_g, *ln1_b, *ffn_w1, *ffn_b1, *ffn_w2, *ffn_b2;
    const float *ln2_g, *ln2_b, *act_w1, *act_b1, *act_w2, *act_b2, *act_w3, *act_b3;
    const float *cr_w1, *cr_b1, *cr_w2, *cr_b2, *cr_w3, *cr_b3;
    float* out;
    ushort *w1T, *w2T, *qkvT, *H1bf, *Y31bf, *featbf;
    float *QKV, *Psc, *Dbuf, *ylast, *y1, *y2;
    float *P_enc1, *P_enc2, *P_attn, *P_atp, *P_h, *P_z, *P_a1, *P_a2, *P_a3;
};

__global__ __launch_bounds__(256)
void mega(KP p)
{
    __shared__ __align__(16) char smem[51200];
    float* lds = (float*)smem;
    cg::grid_group grid = cg::this_grid();
    const int nb = gridDim.x;

    // ---- P0: weight transposes + feat31 bf16 convert + enc-last stage1 partials ----
    for (int u = blockIdx.x; u < 1792; u += nb) {
        if (u < 128) {
            g32_body<64>(p.features + (size_t)1023 * FDIM, (long)TDIM * FDIM,
                         nullptr, 0, nullptr, 0,
                         p.enc_w1, DDIM, p.P_enc1, 512, 1024, u & 7, u >> 3, lds);
        } else if (u < 640) {
            int v = u - 128; convT_body(p.enc_w1, 512, 0, p.w1T, 1024, v & 15, v >> 4, lds);
        } else if (u < 896) {
            int v = u - 640; convT_body(p.enc_w2, 512, 0, p.w2T, 512, v & 15, v >> 4, lds);
        } else if (u < 1664) {
            int v = u - 896; convT_body(p.qkv_w, 1536, 0, p.qkvT, 512, v % 48, v / 48, lds);
        } else {
            int v = u - 1664;  // 128 units x 2048 float4 over features[31]
            const float4* src = (const float4*)(p.features + (size_t)31 * TDIM * FDIM);
            for (int e = v * 2048 + threadIdx.x; e < v * 2048 + 2048; e += 256) {
                float4 w = src[e];
                ushort4 o;
                o.x = f2bf(w.x); o.y = f2bf(w.y); o.z = f2bf(w.z); o.w = f2bf(w.w);
                ((ushort4*)p.featbf)[e] = o;
            }
        }
        __syncthreads();
    }
    grid.sync();

    // ---- P1: MFMA H1 + enc-last stage2 partials ----
    for (int u = blockIdx.x; u < 192; u += nb) {
        if (u < 128)
            mfma_body(p.featbf, 1024, p.w1T, p.enc_b1, nullptr, 0, p.H1bf, 512,
                      1024, 1, 0, u & 7, u >> 3, smem);
        else {
            int v = u - 128;
            g32_body<64>(nullptr, 0, p.P_enc1, 16, p.enc_b1, 1,
                         p.enc_w2, 512, p.P_enc2, 512, 512, v & 7, v >> 3, lds);
        }
        __syncthreads();
    }
    grid.sync();

    // ---- P2: MFMA Y31bf + ylast finalize ----
    for (int u = blockIdx.x; u < 160; u += nb) {
        if (u < 128)
            mfma_body(p.H1bf, 512, p.w2T, p.enc_b2, nullptr, 0, p.Y31bf, 512,
                      512, 1, 1, u & 7, u >> 3, smem);
        else {
            int m = u - 128;
            #pragma unroll
            for (int half = 0; half < 2; ++half) {
                int c = threadIdx.x + half * 256;
                float s = p.enc_b2[c];
                for (int cc = 0; cc < 8; ++cc) s += p.P_enc2[(size_t)(cc * 32 + m) * 512 + c];
                s = fmaxf(s, 0.f) + posenc_val(1023, c);
                p.ylast[m * 512 + c] = s;
            }
        }
        __syncthreads();
    }
    grid.sync();

    // ---- P3: MFMA QKV (f32 out, ld 1536) ----
    for (int u = blockIdx.x; u < 384; u += nb) {
        mfma_body(p.Y31bf, 512, p.qkvT, p.qkv_b, p.QKV, 1536, nullptr, 0,
                  512, 0, 0, u % 24, u / 24, smem);
        __syncthreads();
    }
    grid.sync();

    // ---- P4: scores partials ----
    for (int u = blockIdx.x; u < 64; u += nb) {
        scores_body(p.QKV, p.Psc, u & 15, u >> 4, smem);
        __syncthreads();
    }
    grid.sync();

    // ---- P5: dual softmax + diff ----
    for (int u = blockIdx.x; u < 32; u += nb) {
        softmax_body(p.Psc, p.lam, p.Dbuf, u, lds);
        __syncthreads();
    }
    grid.sync();

    // ---- P6: PV partials ----
    for (int u = blockIdx.x; u < 128; u += nb) {
        g32_body<64>(p.Dbuf, 1024, nullptr, 0, nullptr, 0,
                     p.QKV + 1024, 1536, p.P_attn, 512, 1024, u & 7, u >> 3, lds);
        __syncthreads();
    }
    grid.sync();

    // ---- P7: out-projection partials (reduce P_attn) ----
    for (int u = blockIdx.x; u < 64; u += nb) {
        g32_body<64>(nullptr, 0, p.P_attn, 16, nullptr, 0,
                     p.out_w, 512, p.P_atp, 512, 512, u & 7, u >> 3, lds);
        __syncthreads();
    }
    grid.sync();

    // ---- P8: LN1 ----
    for (int u = blockIdx.x; u < 32; u += nb) {
        ln_body(p.P_atp, 8, p.out_b, p.ylast, p.ln1_g, p.ln1_b, p.y1, u, lds);
        __syncthreads();
    }
    grid.sync();

    // ---- P9: FFN1 partials ----
    for (int u = blockIdx.x; u < 128; u += nb) {
        g32_body<64>(p.y1, 512, nullptr, 0, nullptr, 0,
                     p.ffn_w1, 1024, p.P_h, 1024, 512, u & 15, u >> 4, lds);
        __syncthreads();
    }
    grid.sync();

    // ---- P10: FFN2 partials (reduce+relu P_h) ----
    for (int u = blockIdx.x; u < 128; u += nb) {
        g32_body<64>(nullptr, 0, p.P_h, 8, p.ffn_b1, 1,
                     p.ffn_w2, 512, p.P_z, 512, 1024, u & 7, u >> 3, lds);
        __syncthreads();
    }
    grid.sync();

    // ---- P11: LN2 ----
    for (int u = blockIdx.x; u < 32; u += nb) {
        ln_body(p.P_z, 16, p.ffn_b2, p.y1, p.ln2_g, p.ln2_b, p.y2, u, lds);
        __syncthreads();
    }
    grid.sync();

    // ---- P12: heads layer1 (dual) ----
    for (int u = blockIdx.x; u < 256; u += nb) {
        int z = u >> 7, v = u & 127;
        g32_body<64>(p.y2, 512, nullptr, 0, nullptr, 0,
                     z ? p.cr_w1 : p.act_w1, 1024,
                     p.P_a1 + (size_t)z * 8 * 32 * 1024, 1024, 512, v & 15, v >> 4, lds);
        __syncthreads();
    }
    grid.sync();

    // ---- P13: heads layer2 (dual, reduce+relu P_a1) ----
    for (int u = blockIdx.x; u < 512; u += nb) {
        int z = u >> 8, v = u & 255;
        g32_body<128>(nullptr, 0, p.P_a1 + (size_t)z * 8 * 32 * 1024, 8,
                      z ? p.cr_b1 : p.act_b1, 1,
                      z ? p.cr_w2 : p.act_w2, 2048,
                      p.P_a2 + (size_t)z * 8 * 32 * 2048, 2048, 1024, v & 31, v >> 5, lds);
        __syncthreads();
    }
    grid.sync();

    // ---- P14: heads layer3 (dual, reduce+relu P_a2) ----
    for (int u = blockIdx.x; u < 128; u += nb) {
        int z = u >> 6, v = u & 63;
        g32_body<128>(nullptr, 0, p.P_a2 + (size_t)z * 8 * 32 * 2048, 8,
                      z ? p.cr_b2 : p.act_b2, 1,
                      z ? p.cr_w3 : p.act_w3, 256,
                      p.P_a3 + (size_t)z * 16 * 32 * 256, 256, 2048, v & 3, v >> 2, lds);
        __syncthreads();
    }
    grid.sync();

    // ---- P15: final reduce -> out ----
    for (int u = blockIdx.x; u < 64; u += nb) {
        int m = u & 31, z = u >> 5;
        const float* bias = z ? p.cr_b3 : p.act_b3;
        const float* Pz = p.P_a3 + (size_t)z * 16 * 32 * 256;
        int n = threadIdx.x;
        float s = bias[n];
        for (int c = 0; c < 16; ++c) s += Pz[(size_t)(c * 32 + m) * 256 + n];
        p.out[z * 8192 + m * 256 + n] = s;
        __syncthreads();
    }
}

extern "C" void kernel_launch(void* const* d_in, const int* in_sizes, int n_in,
                              void* d_out, int out_size, void* d_ws, size_t ws_size,
                              hipStream_t stream)
{
    char* base = (char*)d_ws;

    KP p;
    p.features = (const float*)d_in[0];
    p.enc_w1 = (const float*)d_in[1];  p.enc_b1 = (const float*)d_in[2];
    p.enc_w2 = (const float*)d_in[3];  p.enc_b2 = (const float*)d_in[4];
    p.qkv_w  = (const float*)d_in[5];  p.qkv_b  = (const float*)d_in[6];
    p.lam    = (const float*)d_in[7];
    p.out_w  = (const float*)d_in[8];  p.out_b  = (const float*)d_in[9];
    p.ln1_g  = (const float*)d_in[10]; p.ln1_b  = (const float*)d_in[11];
    p.ffn_w1 = (const float*)d_in[12]; p.ffn_b1 = (const float*)d_in[13];
    p.ffn_w2 = (const float*)d_in[14]; p.ffn_b2 = (const float*)d_in[15];
    p.ln2_g  = (const float*)d_in[16]; p.ln2_b  = (const float*)d_in[17];
    p.act_w1 = (const float*)d_in[18]; p.act_b1 = (const float*)d_in[19];
    p.act_w2 = (const float*)d_in[20]; p.act_b2 = (const float*)d_in[21];
    p.act_w3 = (const float*)d_in[22]; p.act_b3 = (const float*)d_in[23];
    p.cr_w1  = (const float*)d_in[24]; p.cr_b1  = (const float*)d_in[25];
    p.cr_w2  = (const float*)d_in[26]; p.cr_b2  = (const float*)d_in[27];
    p.cr_w3  = (const float*)d_in[28]; p.cr_b3  = (const float*)d_in[29];
    p.out    = (float*)d_out;

    p.w1T    = (ushort*)(base + 0x000000);   // 512x1024 bf16 (1 MiB)
    p.w2T    = (ushort*)(base + 0x100000);   // 512x512       (0.5 MiB)
    p.qkvT   = (ushort*)(base + 0x180000);   // 1536x512      (1.5 MiB)
    p.H1bf   = (ushort*)(base + 0x300000);   // 1024x512      (1 MiB)
    p.Y31bf  = (ushort*)(base + 0x400000);   // 1024x512      (1 MiB)
    p.QKV    = (float*)(base + 0x500000);    // 1024x1536 f32 (6 MiB)
    p.Psc    = (float*)(base + 0xB00000);    // 4x1024x32
    p.Dbuf   = (float*)(base + 0xB80000);    // 32x1024
    p.ylast  = (float*)(base + 0xBA0000);    // 32x512
    p.y1     = (float*)(base + 0xBB0000);    // 32x512
    p.y2     = (float*)(base + 0xBC0000);    // 32x512
    p.P_enc1 = (float*)(base + 0xC00000);    // 16x32x512
    p.P_enc2 = (float*)(base + 0xD00000);    // 8x32x512
    p.P_attn = (float*)(base + 0xD80000);    // 16x32x512
    p.P_atp  = (float*)(base + 0xE80000);    // 8x32x512
    p.P_h    = (float*)(base + 0xF00000);    // 8x32x1024
    p.P_z    = (float*)(base + 0x1000000);   // 16x32x512
    p.P_a1   = (float*)(base + 0x1100000);   // 2x8x32x1024 (2 MiB)
    p.P_a2   = (float*)(base + 0x1300000);   // 2x8x32x2048 (4 MiB)
    p.P_a3   = (float*)(base + 0x1700000);   // 2x16x32x256 (1 MiB)
    // featbf time-shares the P_a1 region (used only before P12 writes P_a1)
    p.featbf = (ushort*)(base + 0x1100000);  // 1024x1024 bf16 (2 MiB)

    void* kargs[] = { (void*)&p };
    hipLaunchCooperativeKernel((const void*)mega, dim3(256), dim3(256), kargs, 0, stream);
}

// Round 10
// 192.118 us; speedup vs baseline: 2.9260x; 2.9260x over previous
//
#include <hip/hip_runtime.h>
#include <hip/hip_bf16.h>
#include <math.h>

#define TDIM 1024
#define FDIM 1024
#define DDIM 512

typedef __attribute__((ext_vector_type(8))) short bf16x8;
typedef __attribute__((ext_vector_type(8))) ushort u16x8;
typedef __attribute__((ext_vector_type(4))) float f32x4;

__device__ __forceinline__ float posenc_val(int t, int c) {
    int j = c >> 1;
    float dv = expf(-9.210340371976184f * (float)(2 * j) * (1.0f / 512.0f));
    float arg = (float)t * dv;
    return (c & 1) ? cosf(arg) : sinf(arg);
}

__device__ __forceinline__ ushort f2bf(float f) {
    __hip_bfloat16 h = __float2bfloat16(f);
    return *reinterpret_cast<ushort*>(&h);
}

// ================= small-M (32-row) split-K GEMM body (NS sub-steps per chunk) =================
template<int BK, int NS>
__device__ __forceinline__ void g32_body(
    const float* X, long lda,
    const float* Pin, int KCx, const float* xbias, int xrelu,
    const float* W, long ldb,
    float* Pout, int N, int K,
    int bx, int by, float* lds)
{
    float (*Xs)[BK + 4] = (float (*)[BK + 4])lds;
    float (*Ws)[64]     = (float (*)[64])(lds + 32 * (BK + 4));
    const int tid = threadIdx.x;
    const int n0 = bx * 64;

    const int tx = tid & 31;
    const int ty = tid >> 5;
    float acc[4][2] = {};

    for (int st = 0; st < NS; ++st) {
        const int k0 = (by * NS + st) * BK;
        {
            const int m  = tid >> 3;
            const int ks = (tid & 7) * (BK / 8);
            if (Pin) {
                #pragma unroll
                for (int j = 0; j < BK / 32; ++j) {
                    float4 a = make_float4(0.f, 0.f, 0.f, 0.f);
                    for (int c = 0; c < KCx; ++c) {
                        float4 v = *(const float4*)(Pin + (size_t)(c * 32 + m) * K + k0 + ks + j * 4);
                        a.x += v.x; a.y += v.y; a.z += v.z; a.w += v.w;
                    }
                    if (xbias) {
                        float4 bv = *(const float4*)(xbias + k0 + ks + j * 4);
                        a.x += bv.x; a.y += bv.y; a.z += bv.z; a.w += bv.w;
                    }
                    if (xrelu) {
                        a.x = fmaxf(a.x, 0.f); a.y = fmaxf(a.y, 0.f);
                        a.z = fmaxf(a.z, 0.f); a.w = fmaxf(a.w, 0.f);
                    }
                    *(float4*)&Xs[m][ks + j * 4] = a;
                }
            } else {
                const float* src = X + (size_t)m * lda + k0 + ks;
                #pragma unroll
                for (int j = 0; j < BK / 32; ++j)
                    *(float4*)&Xs[m][ks + j * 4] = *(const float4*)(src + j * 4);
            }
        }
        #pragma unroll
        for (int it = 0; it < BK / 16; ++it) {
            int e4  = it * 256 + tid;
            int row = e4 >> 4;
            int c4  = e4 & 15;
            *(float4*)&Ws[row][c4 * 4] = *(const float4*)(W + (size_t)(k0 + row) * ldb + n0 + c4 * 4);
        }
        __syncthreads();

        #pragma unroll 8
        for (int k = 0; k < BK; k += 4) {
            float4 xv[4];
            #pragma unroll
            for (int i = 0; i < 4; ++i) xv[i] = *(const float4*)&Xs[ty * 4 + i][k];
            #pragma unroll
            for (int j = 0; j < 4; ++j) {
                float2 w = *(const float2*)&Ws[k + j][tx * 2];
                #pragma unroll
                for (int i = 0; i < 4; ++i) {
                    float x = ((const float*)&xv[i])[j];
                    acc[i][0] = fmaf(x, w.x, acc[i][0]);
                    acc[i][1] = fmaf(x, w.y, acc[i][1]);
                }
            }
        }
        __syncthreads();
    }
    float* dst = Pout + (size_t)by * 32 * N;
    #pragma unroll
    for (int i = 0; i < 4; ++i)
        *(float2*)(dst + (size_t)(ty * 4 + i) * N + n0 + tx * 2) = make_float2(acc[i][0], acc[i][1]);
}

// generic 3D-grid wrapper (z = dual set)
template<int BK, int NS>
__global__ __launch_bounds__(256) void g32k(
    const float* X0, const float* X1, long lda,
    const float* Pin0, const float* Pin1, int KCx,
    const float* xb0, const float* xb1, int xrelu,
    const float* W0, const float* W1, long ldb,
    float* Pout, int N, int K)
{
    __shared__ __align__(16) float lds[32 * (BK + 4) + BK * 64];
    const int z = blockIdx.z;
    g32_body<BK, NS>(z ? X1 : X0, lda, z ? Pin1 : Pin0, KCx, z ? xb1 : xb0, xrelu,
                     z ? W1 : W0, ldb,
                     Pout + (size_t)z * gridDim.y * 32 * N,
                     N, K, blockIdx.x, blockIdx.y, lds);
}

// ================= convert+transpose body: W[K][ldw] -> Wt[N][K] bf16 =================
__device__ __forceinline__ void convT_body(const float* W, int ldw, int col0,
                                           ushort* Wt, int K, int bx, int by, float* lds)
{
    float (*t)[33] = (float (*)[33])lds;
    const int k0 = by * 32, n0 = bx * 32;
    const int x = threadIdx.x & 31, y = threadIdx.x >> 5;
    #pragma unroll
    for (int yy = y; yy < 32; yy += 8)
        t[yy][x] = W[(size_t)(k0 + yy) * ldw + col0 + n0 + x];
    __syncthreads();
    #pragma unroll
    for (int yy = y; yy < 32; yy += 8)
        Wt[(size_t)(n0 + yy) * K + k0 + x] = f2bf(t[x][yy]);
}

// ================= MFMA bf16 GEMM body (64x64 tile, 4 waves 2x2) =================
// rowmap: A logical row r -> physical row 31 + 32*min(r,31) (Q gather); mvalid: GLOBAL rows written.
__device__ __forceinline__ void mfma_body(
    const void* Aptr, int af32, long lda,
    const ushort* Bt, const float* bias,
    float* C, int ldc, ushort* Cbf, int ldcb,
    int K, int relu, int addpe,
    int bx, int by, char* smem, int rowmap, int mvalid)
{
    ushort* Al = (ushort*)smem;
    ushort* Bl = Al + 64 * 64;
    const int tid = threadIdx.x;
    const int m0 = by * 64;
    const int n0 = bx * 64;
    const int lane = tid & 63;
    const int wv = tid >> 6;
    const int wr = wv >> 1, wc = wv & 1;
    const int fr = lane & 15, g = lane >> 4;

    f32x4 acc[2][2] = {};

    const int r0 = tid >> 3;
    const int c0 = tid & 7;

    for (int k0 = 0; k0 < K; k0 += 64) {
        #pragma unroll
        for (int it = 0; it < 2; ++it) {
            int r = r0 + it * 32;
            int ar = rowmap ? (31 + 32 * (r < 32 ? r : 31)) : (m0 + r);
            if (af32) {
                const float* Af = (const float*)Aptr;
                const float* s = Af + (size_t)ar * lda + k0 + c0 * 8;
                float4 u = *(const float4*)s;
                float4 v = *(const float4*)(s + 4);
                u16x8 pv;
                pv[0] = f2bf(u.x); pv[1] = f2bf(u.y); pv[2] = f2bf(u.z); pv[3] = f2bf(u.w);
                pv[4] = f2bf(v.x); pv[5] = f2bf(v.y); pv[6] = f2bf(v.z); pv[7] = f2bf(v.w);
                *(u16x8*)((char*)Al + r * 128 + ((c0 ^ (r & 7)) << 4)) = pv;
            } else {
                const ushort* Au = (const ushort*)Aptr;
                uint4 va = *(const uint4*)(Au + (size_t)ar * lda + k0 + c0 * 8);
                *(uint4*)((char*)Al + r * 128 + ((c0 ^ (r & 7)) << 4)) = va;
            }
            uint4 vb = *(const uint4*)(Bt + (size_t)(n0 + r) * K + k0 + c0 * 8);
            *(uint4*)((char*)Bl + r * 128 + ((c0 ^ (r & 7)) << 4)) = vb;
        }
        __syncthreads();
        #pragma unroll
        for (int h = 0; h < 2; ++h) {
            bf16x8 af[2], bff[2];
            #pragma unroll
            for (int i = 0; i < 2; ++i) {
                int row = wr * 32 + i * 16 + fr;
                af[i] = *(const bf16x8*)((const char*)Al + row * 128 + (((h * 4 + g) ^ (row & 7)) << 4));
                int col = wc * 32 + i * 16 + fr;
                bff[i] = *(const bf16x8*)((const char*)Bl + col * 128 + (((h * 4 + g) ^ (col & 7)) << 4));
            }
            #pragma unroll
            for (int i = 0; i < 2; ++i)
                #pragma unroll
                for (int j = 0; j < 2; ++j)
                    acc[i][j] = __builtin_amdgcn_mfma_f32_16x16x32_bf16(af[i], bff[j], acc[i][j], 0, 0, 0);
        }
        __syncthreads();
    }

    #pragma unroll
    for (int j = 0; j < 2; ++j) {
        int n = n0 + wc * 32 + j * 16 + fr;
        float bv = bias ? bias[n] : 0.f;
        #pragma unroll
        for (int i = 0; i < 2; ++i) {
            #pragma unroll
            for (int q = 0; q < 4; ++q) {
                int m = m0 + wr * 32 + i * 16 + g * 4 + q;
                if (m >= mvalid) continue;
                float v = acc[i][j][q] + bv;
                if (relu) v = fmaxf(v, 0.f);
                if (addpe) v += posenc_val(m, n);
                if (C)   C[(size_t)m * ldc + n] = v;
                if (Cbf) Cbf[(size_t)m * ldcb + n] = f2bf(v);
            }
        }
    }
}

// ================= D1: weight transposes + enc-last stage1 partials =================
__global__ __launch_bounds__(256) void prep_k(
    const float* features, const float* enc_w1, const float* qkv_w, const float* enc_w2,
    ushort* w1T, ushort* w2T, ushort* qkvT, float* P_enc1)
{
    __shared__ __align__(16) float lds[6272];
    int t = blockIdx.x;
    if (t < 128) {
        g32_body<64, 1>(features + (size_t)1023 * FDIM, (long)TDIM * FDIM,
                        nullptr, 0, nullptr, 0,
                        enc_w1, DDIM, P_enc1, 512, 1024, t & 7, t >> 3, lds);
    } else if (t < 640) {
        int u = t - 128; convT_body(enc_w1, 512, 0, w1T, 1024, u & 15, u >> 4, lds);
    } else if (t < 896) {
        int u = t - 640; convT_body(enc_w2, 512, 0, w2T, 512, u & 15, u >> 4, lds);
    } else {
        int u = t - 896; convT_body(qkv_w, 1536, 0, qkvT, 512, u % 48, u / 48, lds);
    }
}

// ================= D2: MFMA H1 (f32 A on-the-fly) + enc-last stage2 partials =================
__global__ __launch_bounds__(256) void stage2_k(
    const float* features31, const ushort* w1T, const float* enc_b1, ushort* H1bf,
    const float* P_enc1, const float* enc_w2, float* P_enc2)
{
    __shared__ __align__(16) char smem[51200];
    int t = blockIdx.x;
    if (t < 128) {
        mfma_body(features31, 1, 1024, w1T, enc_b1, nullptr, 0, H1bf, 512,
                  1024, 1, 0, t & 7, t >> 3, smem, 0, 1024);
    } else {
        int v = t - 128;
        g32_body<64, 1>(nullptr, 0, P_enc1, 16, enc_b1, 1,
                        enc_w2, 512, P_enc2, 512, 512, v & 7, v >> 3, (float*)smem);
    }
}

// ================= D3: MFMA Y31bf + ylast finalize =================
__global__ __launch_bounds__(256) void stage3_k(
    const ushort* H1bf, const ushort* w2T, const float* enc_b2, ushort* Y31bf,
    const float* P_enc2, float* ylast)
{
    __shared__ __align__(16) char smem[16384];
    int t = blockIdx.x;
    if (t < 128) {
        mfma_body(H1bf, 0, 512, w2T, enc_b2, nullptr, 0, Y31bf, 512,
                  512, 1, 1, t & 7, t >> 3, smem, 0, 1024);
    } else {
        int m = t - 128;
        #pragma unroll
        for (int half = 0; half < 2; ++half) {
            int c = threadIdx.x + half * 256;
            float s = enc_b2[c];
            for (int cc = 0; cc < 8; ++cc) s += P_enc2[(size_t)(cc * 32 + m) * 512 + c];
            s = fmaxf(s, 0.f) + posenc_val(1023, c);
            ylast[m * 512 + c] = s;
        }
    }
}

// ================= D4: MFMA KV (N=1024) + MFMA Q32 (strided rows) =================
__global__ __launch_bounds__(256) void stage4_k(
    const ushort* Y31bf, const ushort* qkvT, const float* qkv_b,
    float* KV, float* Q32)
{
    __shared__ __align__(16) char smem[16384];
    int u = blockIdx.x;
    if (u < 256) {
        // FIX: mvalid is GLOBAL row count -> 1024 (was 64; by>=1 tiles wrote nothing)
        mfma_body(Y31bf, 0, 512, qkvT + (size_t)512 * 512, qkv_b + 512,
                  KV, 1024, nullptr, 0, 512, 0, 0, u & 15, u >> 4, smem, 0, 1024);
    } else {
        mfma_body(Y31bf, 0, 512, qkvT, qkv_b,
                  Q32, 512, nullptr, 0, 512, 0, 0, u - 256, 0, smem, 1, 32);
    }
}

// ================= D5: attention scores partials (per 128-dim chunk) =================
__global__ __launch_bounds__(256) void scores_kernel(
    const float* __restrict__ KV, const float* __restrict__ Q32, float* __restrict__ Psc)
{
    __shared__ float Kt[64][132];
    __shared__ float Qt[32][133];
    const int tid = threadIdx.x;
    const int s0 = blockIdx.x * 64;
    const int k0 = blockIdx.y * 128;

    #pragma unroll
    for (int it = 0; it < 8; ++it) {
        int e4 = it * 256 + tid;
        int r  = e4 >> 5;
        int c4 = e4 & 31;
        float4 v = *(const float4*)(KV + (size_t)(s0 + r) * 1024 + k0 + c4 * 4);
        *(float4*)&Kt[r][c4 * 4] = v;
    }
    #pragma unroll
    for (int it = 0; it < 4; ++it) {
        int e4 = it * 256 + tid;
        int r  = e4 >> 5;
        int c4 = e4 & 31;
        float4 v = *(const float4*)(Q32 + (size_t)r * 512 + k0 + c4 * 4);
        Qt[r][c4 * 4 + 0] = v.x;
        Qt[r][c4 * 4 + 1] = v.y;
        Qt[r][c4 * 4 + 2] = v.z;
        Qt[r][c4 * 4 + 3] = v.w;
    }
    __syncthreads();

    const int i  = tid & 31;
    const int sg = tid >> 5;
    float acc[8] = {};
    for (int k = 0; k < 128; ++k) {
        float q = Qt[i][k];
        #pragma unroll
        for (int j = 0; j < 8; ++j)
            acc[j] = fmaf(Kt[sg * 8 + j][k], q, acc[j]);
    }
    float* dst = Psc + (size_t)blockIdx.y * 1024 * 32;
    #pragma unroll
    for (int j = 0; j < 8; ++j)
        dst[(size_t)(s0 + sg * 8 + j) * 32 + i] = acc[j];
}

// ================= D6: dual softmax + diff: D[i][s] = a1 - lam*a2 =================
__global__ __launch_bounds__(256) void softmax_diff(
    const float* __restrict__ Psc, const float* __restrict__ lam_p, float* __restrict__ D)
{
    __shared__ float sc1[TDIM];
    __shared__ float sc2[TDIM];
    __shared__ float red[256];
    const int i = blockIdx.x;
    const int tid = threadIdx.x;
    const float scale = 0.08838834764831845f; // 1/sqrt(128)
    for (int s = tid; s < TDIM; s += 256) {
        float a = Psc[(size_t)s * 32 + i] + Psc[(size_t)(1024 + s) * 32 + i];
        float b = Psc[(size_t)(2048 + s) * 32 + i] + Psc[(size_t)(3072 + s) * 32 + i];
        sc1[s] = a * scale;
        sc2[s] = b * scale;
    }
    __syncthreads();
    float m1 = -INFINITY, m2 = -INFINITY;
    for (int s = tid; s < TDIM; s += 256) { m1 = fmaxf(m1, sc1[s]); m2 = fmaxf(m2, sc2[s]); }
    red[tid] = m1; __syncthreads();
    for (int o = 128; o > 0; o >>= 1) { if (tid < o) red[tid] = fmaxf(red[tid], red[tid + o]); __syncthreads(); }
    m1 = red[0]; __syncthreads();
    red[tid] = m2; __syncthreads();
    for (int o = 128; o > 0; o >>= 1) { if (tid < o) red[tid] = fmaxf(red[tid], red[tid + o]); __syncthreads(); }
    m2 = red[0]; __syncthreads();
    float t1 = 0.f, t2 = 0.f;
    for (int s = tid; s < TDIM; s += 256) { t1 += expf(sc1[s] - m1); t2 += expf(sc2[s] - m2); }
    red[tid] = t1; __syncthreads();
    for (int o = 128; o > 0; o >>= 1) { if (tid < o) red[tid] += red[tid + o]; __syncthreads(); }
    t1 = red[0]; __syncthreads();
    red[tid] = t2; __syncthreads();
    for (int o = 128; o > 0; o >>= 1) { if (tid < o) red[tid] += red[tid + o]; __syncthreads(); }
    t2 = red[0]; __syncthreads();
    const float inv1 = 1.f / t1, inv2 = 1.f / t2;
    const float lam = *lam_p;
    for (int s = tid; s < TDIM; s += 256)
        D[(size_t)i * TDIM + s] = expf(sc1[s] - m1) * inv1 - lam * expf(sc2[s] - m2) * inv2;
}

// ================= fused LN + GEMM: X = LN(R + sum(Pin)+inb)*g+b, Pout[by] = Xslice @ W =================
__global__ __launch_bounds__(256) void lngemm_k(
    const float* __restrict__ Pin, int KC,
    const float* __restrict__ inb, const float* __restrict__ R,
    const float* __restrict__ g, const float* __restrict__ b,
    const float* __restrict__ W0, const float* __restrict__ W1, int ldw,
    float* __restrict__ Pout, int N, float* __restrict__ Yout)
{
    __shared__ float Xs[32][68];
    __shared__ float Ws[64][64];
    __shared__ float st1[32][8];
    __shared__ float st2[32][8];
    __shared__ float mu_s[32], inv_s[32];
    const int tid = threadIdx.x;
    const int n0 = blockIdx.x * 64, k0 = blockIdx.y * 64;
    const float* W = blockIdx.z ? W1 : W0;

    // pass 1: row stats over full 512
    {
        const int i = tid >> 3, p = tid & 7;
        float s1 = 0.f, s2 = 0.f;
        for (int q4 = 0; q4 < 16; ++q4) {
            int n = p * 64 + q4 * 4;
            float4 v = *(const float4*)(inb + n);
            float4 r = *(const float4*)(R + i * 512 + n);
            v.x += r.x; v.y += r.y; v.z += r.z; v.w += r.w;
            for (int c = 0; c < KC; ++c) {
                float4 pv = *(const float4*)(Pin + (size_t)(c * 32 + i) * 512 + n);
                v.x += pv.x; v.y += pv.y; v.z += pv.z; v.w += pv.w;
            }
            s1 += v.x + v.y + v.z + v.w;
            s2 += v.x * v.x + v.y * v.y + v.z * v.z + v.w * v.w;
        }
        st1[i][p] = s1; st2[i][p] = s2;
    }
    __syncthreads();
    if (tid < 32) {
        float s1 = 0.f, s2 = 0.f;
        #pragma unroll
        for (int p = 0; p < 8; ++p) { s1 += st1[tid][p]; s2 += st2[tid][p]; }
        float mu = s1 * (1.0f / 512.0f);
        float var = s2 * (1.0f / 512.0f) - mu * mu;
        mu_s[tid] = mu;
        inv_s[tid] = 1.0f / sqrtf(var + 1e-5f);
    }
    // W stage
    #pragma unroll
    for (int it = 0; it < 4; ++it) {
        int e4 = it * 256 + tid;
        int row = e4 >> 4, c4 = e4 & 15;
        *(float4*)&Ws[row][c4 * 4] = *(const float4*)(W + (size_t)(k0 + row) * ldw + n0 + c4 * 4);
    }
    __syncthreads();
    // pass 2: normalized slice
    {
        const int m = tid >> 3, f = tid & 7;
        float mu = mu_s[m], iv = inv_s[m];
        #pragma unroll
        for (int h = 0; h < 2; ++h) {
            int n = k0 + f * 8 + h * 4;
            float4 v = *(const float4*)(inb + n);
            float4 r = *(const float4*)(R + m * 512 + n);
            v.x += r.x; v.y += r.y; v.z += r.z; v.w += r.w;
            for (int c = 0; c < KC; ++c) {
                float4 pv = *(const float4*)(Pin + (size_t)(c * 32 + m) * 512 + n);
                v.x += pv.x; v.y += pv.y; v.z += pv.z; v.w += pv.w;
            }
            float4 gg = *(const float4*)(g + n);
            float4 bb = *(const float4*)(b + n);
            float4 y;
            y.x = (v.x - mu) * iv * gg.x + bb.x;
            y.y = (v.y - mu) * iv * gg.y + bb.y;
            y.z = (v.z - mu) * iv * gg.z + bb.z;
            y.w = (v.w - mu) * iv * gg.w + bb.w;
            *(float4*)&Xs[m][f * 8 + h * 4] = y;
            if (Yout && blockIdx.x == 0)
                *(float4*)(Yout + m * 512 + n) = y;
        }
    }
    __syncthreads();
    // matmul (BK=64)
    const int tx = tid & 31, ty = tid >> 5;
    float acc[4][2] = {};
    #pragma unroll 8
    for (int k = 0; k < 64; k += 4) {
        float4 xv[4];
        #pragma unroll
        for (int i = 0; i < 4; ++i) xv[i] = *(const float4*)&Xs[ty * 4 + i][k];
        #pragma unroll
        for (int j = 0; j < 4; ++j) {
            float2 w = *(const float2*)&Ws[k + j][tx * 2];
            #pragma unroll
            for (int i = 0; i < 4; ++i) {
                float x = ((const float*)&xv[i])[j];
                acc[i][0] = fmaf(x, w.x, acc[i][0]);
                acc[i][1] = fmaf(x, w.y, acc[i][1]);
            }
        }
    }
    float* dst = Pout + (size_t)(blockIdx.z * gridDim.y + blockIdx.y) * 32 * N;
    #pragma unroll
    for (int i = 0; i < 4; ++i)
        *(float2*)(dst + (size_t)(ty * 4 + i) * N + n0 + tx * 2) = make_float2(acc[i][0], acc[i][1]);
}

// ================= final head reduce -> out =================
__global__ __launch_bounds__(256) void fin_out(
    const float* __restrict__ P, const float* __restrict__ b0, const float* __restrict__ b1,
    float* __restrict__ out)
{
    const int m = blockIdx.x;
    const int z = blockIdx.y;
    const int n = threadIdx.x;
    const float* bias = z ? b1 : b0;
    const float* Pz = P + (size_t)z * 16 * 32 * 256;
    float s = bias[n];
    for (int c = 0; c < 16; ++c) s += Pz[(size_t)(c * 32 + m) * 256 + n];
    out[z * 8192 + m * 256 + n] = s;
}

extern "C" void kernel_launch(void* const* d_in, const int* in_sizes, int n_in,
                              void* d_out, int out_size, void* d_ws, size_t ws_size,
                              hipStream_t stream)
{
    const float* features = (const float*)d_in[0];
    const float* enc_w1 = (const float*)d_in[1];
    const float* enc_b1 = (const float*)d_in[2];
    const float* enc_w2 = (const float*)d_in[3];
    const float* enc_b2 = (const float*)d_in[4];
    const float* qkv_w  = (const float*)d_in[5];
    const float* qkv_b  = (const float*)d_in[6];
    const float* lam    = (const float*)d_in[7];
    const float* out_w  = (const float*)d_in[8];
    const float* out_b  = (const float*)d_in[9];
    const float* ln1_g  = (const float*)d_in[10];
    const float* ln1_b  = (const float*)d_in[11];
    const float* ffn_w1 = (const float*)d_in[12];
    const float* ffn_b1 = (const float*)d_in[13];
    const float* ffn_w2 = (const float*)d_in[14];
    const float* ffn_b2 = (const float*)d_in[15];
    const float* ln2_g  = (const float*)d_in[16];
    const float* ln2_b  = (const float*)d_in[17];
    const float* act_w1 = (const float*)d_in[18];
    const float* act_b1 = (const float*)d_in[19];
    const float* act_w2 = (const float*)d_in[20];
    const float* act_b2 = (const float*)d_in[21];
    const float* act_w3 = (const float*)d_in[22];
    const float* act_b3 = (const float*)d_in[23];
    const float* cr_w1  = (const float*)d_in[24];
    const float* cr_b1  = (const float*)d_in[25];
    const float* cr_w2  = (const float*)d_in[26];
    const float* cr_b2  = (const float*)d_in[27];
    const float* cr_w3  = (const float*)d_in[28];
    const float* cr_b3  = (const float*)d_in[29];
    float* out = (float*)d_out;

    // ---------------- workspace (byte offsets; liveness-checked reuse) ----------------
    char* base = (char*)d_ws;
    float*  KV     = (float*)(base + 0x000000);    // [1024][1024], D4->D7 (4 MiB)
    float*  Q32    = (float*)(base + 0x400000);    // [32][512], D4->D5
    float*  P_enc1 = (float*)(base + 0x420000);    // 16x32x512, D1->D2 (1 MiB)
    float*  P_enc2 = (float*)(base + 0x520000);    // 8x32x512, D2->D3 (0.5 MiB)
    float*  ylast  = (float*)(base + 0x5A0000);    // 32x512, D3->D9
    float*  y1     = (float*)(base + 0x5B0000);    // 32x512, D9->D11
    ushort* w1T    = (ushort*)(base + 0x600000);   // 512x1024 bf16, D1->D2 (1 MiB)
    ushort* w2T    = (ushort*)(base + 0x700000);   // 512x512, D1->D3 (0.5 MiB)
    ushort* qkvT   = (ushort*)(base + 0x780000);   // 1536x512, D1->D4 (1.5 MiB)
    ushort* H1bf   = (ushort*)(base + 0x900000);   // 1024x512, D2->D3 (1 MiB)
    ushort* Y31bf  = (ushort*)(base + 0xA00000);   // 1024x512, D3->D4 (1 MiB)
    float*  Psc    = (float*)(base + 0xD00000);    // 4x1024x32, D5->D6 (512 KiB)
    float*  Dbuf   = (float*)(base + 0xD80000);    // 32x1024, D6->D7 (128 KiB)
    float*  P_attn = (float*)(base + 0xE00000);    // 8x32x512, D7->D8 (512 KiB)
    float*  P_atp  = (float*)(base + 0xE80000);    // 4x32x512, D8->D9 (256 KiB)
    float*  P_h    = (float*)(base + 0xF00000);    // 8x32x1024, D9->D10 (1 MiB)
    float*  P_z    = (float*)(base + 0x1000000);   // 4x32x512, D10->D11 (256 KiB)
    // reuse dead regions:
    float*  P_a1   = (float*)(base + 0x000000);    // 2x8x32x1024, D11->D12 (2 MiB, over KV dead after D7)
    float*  P_a2   = (float*)(base + 0x600000);    // 2x8x32x2048, D12->D13 (4 MiB, over w*T/H1bf dead after D4)
    float*  P_a3   = (float*)(base + 0xA00000);    // 2x16x32x256, D13->D14 (1 MiB, over Y31bf dead after D4)

    const float* features31 = features + (size_t)31 * TDIM * FDIM;
    dim3 blk(256);
    const float* NPF = nullptr;

    // D1: transposes + enc-last stage1 partials
    prep_k<<<1664, blk, 0, stream>>>(features, enc_w1, qkv_w, enc_w2, w1T, w2T, qkvT, P_enc1);
    // D2: MFMA H1 + enc-last stage2
    stage2_k<<<192, blk, 0, stream>>>(features31, w1T, enc_b1, H1bf, P_enc1, enc_w2, P_enc2);
    // D3: MFMA Y31bf + ylast
    stage3_k<<<160, blk, 0, stream>>>(H1bf, w2T, enc_b2, Y31bf, P_enc2, ylast);
    // D4: MFMA KV + MFMA Q32 (mvalid fixed)
    stage4_k<<<264, blk, 0, stream>>>(Y31bf, qkvT, qkv_b, KV, Q32);
    // D5: scores partials
    scores_kernel<<<dim3(16, 4), blk, 0, stream>>>(KV, Q32, Psc);
    // D6: dual softmax + diff -> Dbuf
    softmax_diff<<<32, blk, 0, stream>>>(Psc, lam, Dbuf);
    // D7: PV partials (Dbuf @ V)
    g32k<128, 1><<<dim3(8, 8, 1), blk, 0, stream>>>(Dbuf, NPF, 1024, NPF, NPF, 0, NPF, NPF, 0,
                                                    KV + 512, NPF, 1024, P_attn, 512, 1024);
    // D8: out-projection (reduce P_attn on load)
    g32k<128, 1><<<dim3(8, 4, 1), blk, 0, stream>>>(NPF, NPF, 0, P_attn, NPF, 8, NPF, NPF, 0,
                                                    out_w, NPF, 512, P_atp, 512, 512);
    // D9: FFN1 with LN1 folded (writes y1 via bx==0 blocks)
    lngemm_k<<<dim3(16, 8, 1), blk, 0, stream>>>(P_atp, 4, out_b, ylast, ln1_g, ln1_b,
                                                 ffn_w1, NPF, 1024, P_h, 1024, y1);
    // D10: FFN2 (BK=128 x 2 steps -> KC=4)
    g32k<128, 2><<<dim3(8, 4, 1), blk, 0, stream>>>(NPF, NPF, 0, P_h, NPF, 8, ffn_b1, NPF, 1,
                                                    ffn_w2, NPF, 512, P_z, 512, 1024);
    // D11: heads layer1 with LN2 folded (dual)
    lngemm_k<<<dim3(16, 8, 2), blk, 0, stream>>>(P_z, 4, ffn_b2, y1, ln2_g, ln2_b,
                                                 act_w1, cr_w1, 1024, P_a1, 1024, (float*)nullptr);
    // D12: heads layer2 (dual, reduce+relu P_a1)
    g32k<128, 1><<<dim3(32, 8, 2), blk, 0, stream>>>(NPF, NPF, 0, P_a1, P_a1 + (size_t)8 * 32 * 1024, 8,
                                                     act_b1, cr_b1, 1,
                                                     act_w2, cr_w2, 2048, P_a2, 2048, 1024);
    // D13: heads layer3 (dual, reduce+relu P_a2)
    g32k<128, 1><<<dim3(4, 16, 2), blk, 0, stream>>>(NPF, NPF, 0, P_a2, P_a2 + (size_t)8 * 32 * 2048, 8,
                                                     act_b2, cr_b2, 1,
                                                     act_w3, cr_w3, 256, P_a3, 256, 2048);
    // D14: final reduce -> out
    fin_out<<<dim3(32, 2), blk, 0, stream>>>(P_a3, act_b3, cr_b3, out);
}

// Round 11
// 145.442 us; speedup vs baseline: 3.8651x; 1.3209x over previous
//
#include <hip/hip_runtime.h>
#include <hip/hip_bf16.h>
#include <math.h>

#define TDIM 1024
#define FDIM 1024
#define DDIM 512

typedef __attribute__((ext_vector_type(8))) short bf16x8;
typedef __attribute__((ext_vector_type(8))) ushort u16x8;
typedef __attribute__((ext_vector_type(4))) float f32x4;

__device__ __forceinline__ float posenc_val(int t, int c) {
    int j = c >> 1;
    float dv = expf(-9.210340371976184f * (float)(2 * j) * (1.0f / 512.0f));
    float arg = (float)t * dv;
    return (c & 1) ? cosf(arg) : sinf(arg);
}

__device__ __forceinline__ ushort f2bf(float f) {
    __hip_bfloat16 h = __float2bfloat16(f);
    return *reinterpret_cast<ushort*>(&h);
}

// ================= small-M (32-row) split-K GEMM body =================
template<int BK, int NS>
__device__ __forceinline__ void g32_body(
    const float* X, long lda,
    const float* Pin, int KCx, const float* xbias, int xrelu,
    const float* W, long ldb,
    float* Pout, int N, int K,
    int bx, int by, float* lds)
{
    float (*Xs)[BK + 4] = (float (*)[BK + 4])lds;
    float (*Ws)[64]     = (float (*)[64])(lds + 32 * (BK + 4));
    const int tid = threadIdx.x;
    const int n0 = bx * 64;

    const int tx = tid & 31;
    const int ty = tid >> 5;
    float acc[4][2] = {};

    for (int st = 0; st < NS; ++st) {
        const int k0 = (by * NS + st) * BK;
        {
            const int m  = tid >> 3;
            const int ks = (tid & 7) * (BK / 8);
            if (Pin) {
                #pragma unroll
                for (int j = 0; j < BK / 32; ++j) {
                    float4 a = make_float4(0.f, 0.f, 0.f, 0.f);
                    for (int c = 0; c < KCx; ++c) {
                        float4 v = *(const float4*)(Pin + (size_t)(c * 32 + m) * K + k0 + ks + j * 4);
                        a.x += v.x; a.y += v.y; a.z += v.z; a.w += v.w;
                    }
                    if (xbias) {
                        float4 bv = *(const float4*)(xbias + k0 + ks + j * 4);
                        a.x += bv.x; a.y += bv.y; a.z += bv.z; a.w += bv.w;
                    }
                    if (xrelu) {
                        a.x = fmaxf(a.x, 0.f); a.y = fmaxf(a.y, 0.f);
                        a.z = fmaxf(a.z, 0.f); a.w = fmaxf(a.w, 0.f);
                    }
                    *(float4*)&Xs[m][ks + j * 4] = a;
                }
            } else {
                const float* src = X + (size_t)m * lda + k0 + ks;
                #pragma unroll
                for (int j = 0; j < BK / 32; ++j)
                    *(float4*)&Xs[m][ks + j * 4] = *(const float4*)(src + j * 4);
            }
        }
        #pragma unroll
        for (int it = 0; it < BK / 16; ++it) {
            int e4  = it * 256 + tid;
            int row = e4 >> 4;
            int c4  = e4 & 15;
            *(float4*)&Ws[row][c4 * 4] = *(const float4*)(W + (size_t)(k0 + row) * ldb + n0 + c4 * 4);
        }
        __syncthreads();

        #pragma unroll 8
        for (int k = 0; k < BK; k += 4) {
            float4 xv[4];
            #pragma unroll
            for (int i = 0; i < 4; ++i) xv[i] = *(const float4*)&Xs[ty * 4 + i][k];
            #pragma unroll
            for (int j = 0; j < 4; ++j) {
                float2 w = *(const float2*)&Ws[k + j][tx * 2];
                #pragma unroll
                for (int i = 0; i < 4; ++i) {
                    float x = ((const float*)&xv[i])[j];
                    acc[i][0] = fmaf(x, w.x, acc[i][0]);
                    acc[i][1] = fmaf(x, w.y, acc[i][1]);
                }
            }
        }
        __syncthreads();
    }
    float* dst = Pout + (size_t)by * 32 * N;
    #pragma unroll
    for (int i = 0; i < 4; ++i)
        *(float2*)(dst + (size_t)(ty * 4 + i) * N + n0 + tx * 2) = make_float2(acc[i][0], acc[i][1]);
}

// generic 3D-grid wrapper (z = dual set)
template<int BK, int NS>
__global__ __launch_bounds__(256) void g32k(
    const float* X0, const float* X1, long lda,
    const float* Pin0, const float* Pin1, int KCx,
    const float* xb0, const float* xb1, int xrelu,
    const float* W0, const float* W1, long ldb,
    float* Pout, int N, int K)
{
    __shared__ __align__(16) float lds[32 * (BK + 4) + BK * 64];
    const int z = blockIdx.z;
    g32_body<BK, NS>(z ? X1 : X0, lda, z ? Pin1 : Pin0, KCx, z ? xb1 : xb0, xrelu,
                     z ? W1 : W0, ldb,
                     Pout + (size_t)z * gridDim.y * 32 * N,
                     N, K, blockIdx.x, blockIdx.y, lds);
}

// ================= convert+transpose body: W[K][ldw] -> Wt[N][K] bf16 =================
__device__ __forceinline__ void convT_body(const float* W, int ldw, int col0,
                                           ushort* Wt, int K, int bx, int by, float* lds)
{
    float (*t)[33] = (float (*)[33])lds;
    const int k0 = by * 32, n0 = bx * 32;
    const int x = threadIdx.x & 31, y = threadIdx.x >> 5;
    #pragma unroll
    for (int yy = y; yy < 32; yy += 8)
        t[yy][x] = W[(size_t)(k0 + yy) * ldw + col0 + n0 + x];
    __syncthreads();
    #pragma unroll
    for (int yy = y; yy < 32; yy += 8)
        Wt[(size_t)(n0 + yy) * K + k0 + x] = f2bf(t[x][yy]);
}

// ================= MFMA bf16 GEMM body (64x64 tile, 4 waves 2x2) =================
// rowmap: A logical row r -> physical row 31 + 32*min(r,31) (Q gather); mvalid: GLOBAL rows written.
__device__ __forceinline__ void mfma_body(
    const void* Aptr, int af32, long lda,
    const ushort* Bt, const float* bias,
    float* C, int ldc, ushort* Cbf, int ldcb,
    int K, int relu, int addpe,
    int bx, int by, char* smem, int rowmap, int mvalid)
{
    ushort* Al = (ushort*)smem;
    ushort* Bl = Al + 64 * 64;
    const int tid = threadIdx.x;
    const int m0 = by * 64;
    const int n0 = bx * 64;
    const int lane = tid & 63;
    const int wv = tid >> 6;
    const int wr = wv >> 1, wc = wv & 1;
    const int fr = lane & 15, g = lane >> 4;

    f32x4 acc[2][2] = {};

    const int r0 = tid >> 3;
    const int c0 = tid & 7;

    for (int k0 = 0; k0 < K; k0 += 64) {
        #pragma unroll
        for (int it = 0; it < 2; ++it) {
            int r = r0 + it * 32;
            int ar = rowmap ? (31 + 32 * (r < 32 ? r : 31)) : (m0 + r);
            if (af32) {
                const float* Af = (const float*)Aptr;
                const float* s = Af + (size_t)ar * lda + k0 + c0 * 8;
                float4 u = *(const float4*)s;
                float4 v = *(const float4*)(s + 4);
                u16x8 pv;
                pv[0] = f2bf(u.x); pv[1] = f2bf(u.y); pv[2] = f2bf(u.z); pv[3] = f2bf(u.w);
                pv[4] = f2bf(v.x); pv[5] = f2bf(v.y); pv[6] = f2bf(v.z); pv[7] = f2bf(v.w);
                *(u16x8*)((char*)Al + r * 128 + ((c0 ^ (r & 7)) << 4)) = pv;
            } else {
                const ushort* Au = (const ushort*)Aptr;
                uint4 va = *(const uint4*)(Au + (size_t)ar * lda + k0 + c0 * 8);
                *(uint4*)((char*)Al + r * 128 + ((c0 ^ (r & 7)) << 4)) = va;
            }
            uint4 vb = *(const uint4*)(Bt + (size_t)(n0 + r) * K + k0 + c0 * 8);
            *(uint4*)((char*)Bl + r * 128 + ((c0 ^ (r & 7)) << 4)) = vb;
        }
        __syncthreads();
        #pragma unroll
        for (int h = 0; h < 2; ++h) {
            bf16x8 af[2], bff[2];
            #pragma unroll
            for (int i = 0; i < 2; ++i) {
                int row = wr * 32 + i * 16 + fr;
                af[i] = *(const bf16x8*)((const char*)Al + row * 128 + (((h * 4 + g) ^ (row & 7)) << 4));
                int col = wc * 32 + i * 16 + fr;
                bff[i] = *(const bf16x8*)((const char*)Bl + col * 128 + (((h * 4 + g) ^ (col & 7)) << 4));
            }
            #pragma unroll
            for (int i = 0; i < 2; ++i)
                #pragma unroll
                for (int j = 0; j < 2; ++j)
                    acc[i][j] = __builtin_amdgcn_mfma_f32_16x16x32_bf16(af[i], bff[j], acc[i][j], 0, 0, 0);
        }
        __syncthreads();
    }

    #pragma unroll
    for (int j = 0; j < 2; ++j) {
        int n = n0 + wc * 32 + j * 16 + fr;
        float bv = bias ? bias[n] : 0.f;
        #pragma unroll
        for (int i = 0; i < 2; ++i) {
            #pragma unroll
            for (int q = 0; q < 4; ++q) {
                int m = m0 + wr * 32 + i * 16 + g * 4 + q;
                if (m >= mvalid) continue;
                float v = acc[i][j][q] + bv;
                if (relu) v = fmaxf(v, 0.f);
                if (addpe) v += posenc_val(m, n);
                if (C)   C[(size_t)m * ldc + n] = v;
                if (Cbf) Cbf[(size_t)m * ldcb + n] = f2bf(v);
            }
        }
    }
}

// ================= D1: weight transposes + enc-last stage1 partials =================
__global__ __launch_bounds__(256) void prep_k(
    const float* features, const float* enc_w1, const float* qkv_w, const float* enc_w2,
    ushort* w1T, ushort* w2T, ushort* qkvT, float* P_enc1)
{
    __shared__ __align__(16) float lds[6272];
    int t = blockIdx.x;
    if (t < 128) {
        g32_body<64, 1>(features + (size_t)1023 * FDIM, (long)TDIM * FDIM,
                        nullptr, 0, nullptr, 0,
                        enc_w1, DDIM, P_enc1, 512, 1024, t & 7, t >> 3, lds);
    } else if (t < 640) {
        int u = t - 128; convT_body(enc_w1, 512, 0, w1T, 1024, u & 15, u >> 4, lds);
    } else if (t < 896) {
        int u = t - 640; convT_body(enc_w2, 512, 0, w2T, 512, u & 15, u >> 4, lds);
    } else {
        int u = t - 896; convT_body(qkv_w, 1536, 0, qkvT, 512, u % 48, u / 48, lds);
    }
}

// ================= D2: MFMA H1 (f32 A on-the-fly) + enc-last stage2 partials =================
__global__ __launch_bounds__(256) void stage2_k(
    const float* features31, const ushort* w1T, const float* enc_b1, ushort* H1bf,
    const float* P_enc1, const float* enc_w2, float* P_enc2)
{
    __shared__ __align__(16) char smem[25600];
    int t = blockIdx.x;
    if (t < 128) {
        mfma_body(features31, 1, 1024, w1T, enc_b1, nullptr, 0, H1bf, 512,
                  1024, 1, 0, t & 7, t >> 3, smem, 0, 1024);
    } else {
        int v = t - 128;
        g32_body<64, 1>(nullptr, 0, P_enc1, 16, enc_b1, 1,
                        enc_w2, 512, P_enc2, 512, 512, v & 7, v >> 3, (float*)smem);
    }
}

// ================= D3: MFMA Y31bf + ylast finalize =================
__global__ __launch_bounds__(256) void stage3_k(
    const ushort* H1bf, const ushort* w2T, const float* enc_b2, ushort* Y31bf,
    const float* P_enc2, float* ylast)
{
    __shared__ __align__(16) char smem[16384];
    int t = blockIdx.x;
    if (t < 128) {
        mfma_body(H1bf, 0, 512, w2T, enc_b2, nullptr, 0, Y31bf, 512,
                  512, 1, 1, t & 7, t >> 3, smem, 0, 1024);
    } else {
        int m = t - 128;
        #pragma unroll
        for (int half = 0; half < 2; ++half) {
            int c = threadIdx.x + half * 256;
            float s = enc_b2[c];
            for (int cc = 0; cc < 8; ++cc) s += P_enc2[(size_t)(cc * 32 + m) * 512 + c];
            s = fmaxf(s, 0.f) + posenc_val(1023, c);
            ylast[m * 512 + c] = s;
        }
    }
}

// ================= D4: MFMA KV (N=1024) + MFMA Q32 (strided rows) =================
__global__ __launch_bounds__(256) void stage4_k(
    const ushort* Y31bf, const ushort* qkvT, const float* qkv_b,
    float* KV, float* Q32)
{
    __shared__ __align__(16) char smem[16384];
    int u = blockIdx.x;
    if (u < 256) {
        mfma_body(Y31bf, 0, 512, qkvT + (size_t)512 * 512, qkv_b + 512,
                  KV, 1024, nullptr, 0, 512, 0, 0, u & 15, u >> 4, smem, 0, 1024);
    } else {
        mfma_body(Y31bf, 0, 512, qkvT, qkv_b,
                  Q32, 512, nullptr, 0, 512, 0, 0, u - 256, 0, smem, 1, 32);
    }
}

// ================= D5: attention scores partials (per 128-dim chunk) =================
__global__ __launch_bounds__(256) void scores_kernel(
    const float* __restrict__ KV, const float* __restrict__ Q32, float* __restrict__ Psc)
{
    __shared__ float Kt[64][132];
    __shared__ float Qt[32][133];
    const int tid = threadIdx.x;
    const int s0 = blockIdx.x * 64;
    const int k0 = blockIdx.y * 128;

    #pragma unroll
    for (int it = 0; it < 8; ++it) {
        int e4 = it * 256 + tid;
        int r  = e4 >> 5;
        int c4 = e4 & 31;
        float4 v = *(const float4*)(KV + (size_t)(s0 + r) * 1024 + k0 + c4 * 4);
        *(float4*)&Kt[r][c4 * 4] = v;
    }
    #pragma unroll
    for (int it = 0; it < 4; ++it) {
        int e4 = it * 256 + tid;
        int r  = e4 >> 5;
        int c4 = e4 & 31;
        float4 v = *(const float4*)(Q32 + (size_t)r * 512 + k0 + c4 * 4);
        Qt[r][c4 * 4 + 0] = v.x;
        Qt[r][c4 * 4 + 1] = v.y;
        Qt[r][c4 * 4 + 2] = v.z;
        Qt[r][c4 * 4 + 3] = v.w;
    }
    __syncthreads();

    const int i  = tid & 31;
    const int sg = tid >> 5;
    float acc[8] = {};
    for (int k = 0; k < 128; ++k) {
        float q = Qt[i][k];
        #pragma unroll
        for (int j = 0; j < 8; ++j)
            acc[j] = fmaf(Kt[sg * 8 + j][k], q, acc[j]);
    }
    float* dst = Psc + (size_t)blockIdx.y * 1024 * 32;
    #pragma unroll
    for (int j = 0; j < 8; ++j)
        dst[(size_t)(s0 + sg * 8 + j) * 32 + i] = acc[j];
}

// ================= D6: dual softmax + diff: D[i][s] = a1 - lam*a2 =================
__global__ __launch_bounds__(256) void softmax_diff(
    const float* __restrict__ Psc, const float* __restrict__ lam_p, float* __restrict__ D)
{
    __shared__ float sc1[TDIM];
    __shared__ float sc2[TDIM];
    __shared__ float red[256];
    const int i = blockIdx.x;
    const int tid = threadIdx.x;
    const float scale = 0.08838834764831845f; // 1/sqrt(128)
    for (int s = tid; s < TDIM; s += 256) {
        float a = Psc[(size_t)s * 32 + i] + Psc[(size_t)(1024 + s) * 32 + i];
        float b = Psc[(size_t)(2048 + s) * 32 + i] + Psc[(size_t)(3072 + s) * 32 + i];
        sc1[s] = a * scale;
        sc2[s] = b * scale;
    }
    __syncthreads();
    float m1 = -INFINITY, m2 = -INFINITY;
    for (int s = tid; s < TDIM; s += 256) { m1 = fmaxf(m1, sc1[s]); m2 = fmaxf(m2, sc2[s]); }
    red[tid] = m1; __syncthreads();
    for (int o = 128; o > 0; o >>= 1) { if (tid < o) red[tid] = fmaxf(red[tid], red[tid + o]); __syncthreads(); }
    m1 = red[0]; __syncthreads();
    red[tid] = m2; __syncthreads();
    for (int o = 128; o > 0; o >>= 1) { if (tid < o) red[tid] = fmaxf(red[tid], red[tid + o]); __syncthreads(); }
    m2 = red[0]; __syncthreads();
    float t1 = 0.f, t2 = 0.f;
    for (int s = tid; s < TDIM; s += 256) { t1 += expf(sc1[s] - m1); t2 += expf(sc2[s] - m2); }
    red[tid] = t1; __syncthreads();
    for (int o = 128; o > 0; o >>= 1) { if (tid < o) red[tid] += red[tid + o]; __syncthreads(); }
    t1 = red[0]; __syncthreads();
    red[tid] = t2; __syncthreads();
    for (int o = 128; o > 0; o >>= 1) { if (tid < o) red[tid] += red[tid + o]; __syncthreads(); }
    t2 = red[0]; __syncthreads();
    const float inv1 = 1.f / t1, inv2 = 1.f / t2;
    const float lam = *lam_p;
    for (int s = tid; s < TDIM; s += 256)
        D[(size_t)i * TDIM + s] = expf(sc1[s] - m1) * inv1 - lam * expf(sc2[s] - m2) * inv2;
}

// ================= LN with reduce-on-load (two-pass variance): Y = LN(R + sum(P)+bias)*g + b =================
__global__ __launch_bounds__(256) void ln_red(
    const float* __restrict__ Pin, int KC, const float* __restrict__ bias,
    const float* __restrict__ R, const float* __restrict__ g, const float* __restrict__ b,
    float* __restrict__ Y)
{
    __shared__ float red[256];
    const int m = blockIdx.x;
    const int tid = threadIdx.x;
    float v0 = bias ? bias[tid] : 0.f;
    float v1 = bias ? bias[tid + 256] : 0.f;
    for (int c = 0; c < KC; ++c) {
        v0 += Pin[(size_t)(c * 32 + m) * 512 + tid];
        v1 += Pin[(size_t)(c * 32 + m) * 512 + tid + 256];
    }
    v0 += R[m * 512 + tid];
    v1 += R[m * 512 + tid + 256];
    red[tid] = v0 + v1; __syncthreads();
    for (int o = 128; o > 0; o >>= 1) { if (tid < o) red[tid] += red[tid + o]; __syncthreads(); }
    const float mu = red[0] * (1.0f / 512.0f);
    __syncthreads();
    float d0 = v0 - mu, d1 = v1 - mu;
    red[tid] = d0 * d0 + d1 * d1; __syncthreads();
    for (int o = 128; o > 0; o >>= 1) { if (tid < o) red[tid] += red[tid + o]; __syncthreads(); }
    const float var = red[0] * (1.0f / 512.0f);
    const float inv = 1.0f / sqrtf(var + 1e-5f);
    Y[m * 512 + tid]       = d0 * inv * g[tid]       + b[tid];
    Y[m * 512 + 256 + tid] = d1 * inv * g[256 + tid] + b[256 + tid];
}

// ================= final head reduce -> out =================
__global__ __launch_bounds__(256) void fin_out(
    const float* __restrict__ P, const float* __restrict__ b0, const float* __restrict__ b1,
    float* __restrict__ out)
{
    const int m = blockIdx.x;
    const int z = blockIdx.y;
    const int n = threadIdx.x;
    const float* bias = z ? b1 : b0;
    const float* Pz = P + (size_t)z * 16 * 32 * 256;
    float s = bias[n];
    for (int c = 0; c < 16; ++c) s += Pz[(size_t)(c * 32 + m) * 256 + n];
    out[z * 8192 + m * 256 + n] = s;
}

extern "C" void kernel_launch(void* const* d_in, const int* in_sizes, int n_in,
                              void* d_out, int out_size, void* d_ws, size_t ws_size,
                              hipStream_t stream)
{
    const float* features = (const float*)d_in[0];
    const float* enc_w1 = (const float*)d_in[1];
    const float* enc_b1 = (const float*)d_in[2];
    const float* enc_w2 = (const float*)d_in[3];
    const float* enc_b2 = (const float*)d_in[4];
    const float* qkv_w  = (const float*)d_in[5];
    const float* qkv_b  = (const float*)d_in[6];
    const float* lam    = (const float*)d_in[7];
    const float* out_w  = (const float*)d_in[8];
    const float* out_b  = (const float*)d_in[9];
    const float* ln1_g  = (const float*)d_in[10];
    const float* ln1_b  = (const float*)d_in[11];
    const float* ffn_w1 = (const float*)d_in[12];
    const float* ffn_b1 = (const float*)d_in[13];
    const float* ffn_w2 = (const float*)d_in[14];
    const float* ffn_b2 = (const float*)d_in[15];
    const float* ln2_g  = (const float*)d_in[16];
    const float* ln2_b  = (const float*)d_in[17];
    const float* act_w1 = (const float*)d_in[18];
    const float* act_b1 = (const float*)d_in[19];
    const float* act_w2 = (const float*)d_in[20];
    const float* act_b2 = (const float*)d_in[21];
    const float* act_w3 = (const float*)d_in[22];
    const float* act_b3 = (const float*)d_in[23];
    const float* cr_w1  = (const float*)d_in[24];
    const float* cr_b1  = (const float*)d_in[25];
    const float* cr_w2  = (const float*)d_in[26];
    const float* cr_b2  = (const float*)d_in[27];
    const float* cr_w3  = (const float*)d_in[28];
    const float* cr_b3  = (const float*)d_in[29];
    float* out = (float*)d_out;

    // ---------------- workspace (byte offsets; liveness-checked reuse) ----------------
    char* base = (char*)d_ws;
    float*  KV     = (float*)(base + 0x000000);    // [1024][1024], D4->D7 (4 MiB)
    float*  Q32    = (float*)(base + 0x400000);    // [32][512], D4->D5
    float*  P_enc1 = (float*)(base + 0x420000);    // 16x32x512, D1->D2 (1 MiB)
    float*  P_enc2 = (float*)(base + 0x520000);    // 8x32x512, D2->D3 (0.5 MiB)
    float*  ylast  = (float*)(base + 0x5A0000);    // 32x512, D3->D9
    float*  y1     = (float*)(base + 0x5B0000);    // 32x512, D9->D12
    float*  y2     = (float*)(base + 0x5C0000);    // 32x512, D12->D13
    ushort* w1T    = (ushort*)(base + 0x600000);   // 512x1024 bf16, D1->D2 (1 MiB)
    ushort* w2T    = (ushort*)(base + 0x700000);   // 512x512, D1->D3 (0.5 MiB)
    ushort* qkvT   = (ushort*)(base + 0x780000);   // 1536x512, D1->D4 (1.5 MiB)
    ushort* H1bf   = (ushort*)(base + 0x900000);   // 1024x512, D2->D3 (1 MiB)
    ushort* Y31bf  = (ushort*)(base + 0xA00000);   // 1024x512, D3->D4 (1 MiB)
    float*  Psc    = (float*)(base + 0xD00000);    // 4x1024x32, D5->D6 (512 KiB)
    float*  Dbuf   = (float*)(base + 0xD80000);    // 32x1024, D6->D7 (128 KiB)
    float*  P_attn = (float*)(base + 0xE00000);    // 16x32x512, D7->D8 (1 MiB)
    float*  P_atp  = (float*)(base + 0xF00000);    // 8x32x512, D8->D9 (0.5 MiB)
    float*  P_h    = (float*)(base + 0xF80000);    // 8x32x1024, D10->D11 (1 MiB)
    float*  P_z    = (float*)(base + 0x1080000);   // 16x32x512, D11->D12 (1 MiB)
    // reuse dead regions:
    float*  P_a1   = (float*)(base + 0x000000);    // 2x8x32x1024, D13->D14 (2 MiB, over KV dead after D7)
    float*  P_a2   = (float*)(base + 0x600000);    // 2x8x32x2048, D14->D15 (4 MiB, over w*T/H1bf dead after D4)
    float*  P_a3   = (float*)(base + 0xA00000);    // 2x16x32x256, D15->D16 (1 MiB, over Y31bf dead after D4)

    const float* features31 = features + (size_t)31 * TDIM * FDIM;
    dim3 blk(256);
    const float* NPF = nullptr;

    // D1: transposes + enc-last stage1 partials
    prep_k<<<1664, blk, 0, stream>>>(features, enc_w1, qkv_w, enc_w2, w1T, w2T, qkvT, P_enc1);
    // D2: MFMA H1 + enc-last stage2
    stage2_k<<<192, blk, 0, stream>>>(features31, w1T, enc_b1, H1bf, P_enc1, enc_w2, P_enc2);
    // D3: MFMA Y31bf + ylast
    stage3_k<<<160, blk, 0, stream>>>(H1bf, w2T, enc_b2, Y31bf, P_enc2, ylast);
    // D4: MFMA KV + MFMA Q32
    stage4_k<<<264, blk, 0, stream>>>(Y31bf, qkvT, qkv_b, KV, Q32);
    // D5: scores partials
    scores_kernel<<<dim3(16, 4), blk, 0, stream>>>(KV, Q32, Psc);
    // D6: dual softmax + diff -> Dbuf
    softmax_diff<<<32, blk, 0, stream>>>(Psc, lam, Dbuf);
    // D7: PV partials (Dbuf @ V), BK=64 x 16 chunks, 128 blocks
    g32k<64, 1><<<dim3(8, 16, 1), blk, 0, stream>>>(Dbuf, NPF, 1024, NPF, NPF, 0, NPF, NPF, 0,
                                                    KV + 512, NPF, 1024, P_attn, 512, 1024);
    // D8: out-projection (reduce P_attn KC=16 on load), BK=64 x 8 chunks, 64 blocks
    g32k<64, 1><<<dim3(8, 8, 1), blk, 0, stream>>>(NPF, NPF, 0, P_attn, NPF, 16, NPF, NPF, 0,
                                                   out_w, NPF, 512, P_atp, 512, 512);
    // D9: LN1 (two-pass, reduce P_atp KC=8 + out_b + ylast)
    ln_red<<<32, blk, 0, stream>>>(P_atp, 8, out_b, ylast, ln1_g, ln1_b, y1);
    // D10: FFN1 partials, 128 blocks
    g32k<64, 1><<<dim3(16, 8, 1), blk, 0, stream>>>(y1, NPF, 512, NPF, NPF, 0, NPF, NPF, 0,
                                                    ffn_w1, NPF, 1024, P_h, 1024, 512);
    // D11: FFN2 (reduce+relu P_h KC=8), BK=64 x 16 chunks, 128 blocks
    g32k<64, 1><<<dim3(8, 16, 1), blk, 0, stream>>>(NPF, NPF, 0, P_h, NPF, 8, ffn_b1, NPF, 1,
                                                    ffn_w2, NPF, 512, P_z, 512, 1024);
    // D12: LN2 (two-pass, reduce P_z KC=16 + ffn_b2 + y1)
    ln_red<<<32, blk, 0, stream>>>(P_z, 16, ffn_b2, y1, ln2_g, ln2_b, y2);
    // D13: heads layer1 (dual), 256 blocks
    g32k<64, 1><<<dim3(16, 8, 2), blk, 0, stream>>>(y2, y2, 512, NPF, NPF, 0, NPF, NPF, 0,
                                                    act_w1, cr_w1, 1024, P_a1, 1024, 512);
    // D14: heads layer2 (dual, reduce+relu P_a1), 512 blocks
    g32k<128, 1><<<dim3(32, 8, 2), blk, 0, stream>>>(NPF, NPF, 0, P_a1, P_a1 + (size_t)8 * 32 * 1024, 8,
                                                     act_b1, cr_b1, 1,
                                                     act_w2, cr_w2, 2048, P_a2, 2048, 1024);
    // D15: heads layer3 (dual, reduce+relu P_a2), 128 blocks
    g32k<128, 1><<<dim3(4, 16, 2), blk, 0, stream>>>(NPF, NPF, 0, P_a2, P_a2 + (size_t)8 * 32 * 2048, 8,
                                                     act_b2, cr_b2, 1,
                                                     act_w3, cr_w3, 256, P_a3, 256, 2048);
    // D16: final reduce -> out
    fin_out<<<dim3(32, 2), blk, 0, stream>>>(P_a3, act_b3, cr_b3, out);
}